// Round 3
// baseline (475.628 us; speedup 1.0000x reference)
//
#include <hip/hip_runtime.h>

typedef unsigned short u16;
typedef __attribute__((ext_vector_type(8))) short bf16x8;
typedef __attribute__((ext_vector_type(4))) float f32x4;

#define N_SEQ 256
#define L_RES 384
#define DM 256
#define NH 8
#define DH 32
#define M_ROWS (N_SEQ*L_RES)   // 98304

__device__ __forceinline__ u16 f2b(float f){
    unsigned u = __builtin_bit_cast(unsigned, f);
    u = u + 0x7fffu + ((u >> 16) & 1u);
    return (u16)(u >> 16);
}
__device__ __forceinline__ float b2f(u16 b){
    unsigned u = ((unsigned)b) << 16;
    return __builtin_bit_cast(float, u);
}

// ---------------- Kernel 1: LayerNorm -> bf16 x ----------------
__global__ __launch_bounds__(256) void k_ln(const float* __restrict__ msa,
        const float* __restrict__ lnw, const float* __restrict__ lnb,
        u16* __restrict__ xo){
    int row  = blockIdx.x*4 + (threadIdx.x>>6);
    int lane = threadIdx.x & 63;
    const float4 a = ((const float4*)(msa + (size_t)row*DM))[lane];
    float s  = a.x+a.y+a.z+a.w;
    float ss = a.x*a.x + a.y*a.y + a.z*a.z + a.w*a.w;
    #pragma unroll
    for(int m=1;m<64;m<<=1){ s += __shfl_xor(s,m); ss += __shfl_xor(ss,m); }
    float mu  = s*(1.f/DM);
    float inv = rsqrtf(ss*(1.f/DM) - mu*mu + 1e-5f);
    float4 w = ((const float4*)lnw)[lane];
    float4 b = ((const float4*)lnb)[lane];
    ushort4 o;
    o.x = f2b((a.x-mu)*inv*w.x + b.x);
    o.y = f2b((a.y-mu)*inv*w.y + b.y);
    o.z = f2b((a.z-mu)*inv*w.z + b.z);
    o.w = f2b((a.w-mu)*inv*w.w + b.w);
    ((ushort4*)(xo + (size_t)row*DM))[lane] = o;
}

// ---------------- Kernel 2: fused Q/K/V/G projections ----------------
__global__ __launch_bounds__(256) void k_qkvg(const u16* __restrict__ x,
        const float* __restrict__ wq, const float* __restrict__ wk,
        const float* __restrict__ wv, const float* __restrict__ wg,
        const float* __restrict__ bg,
        u16* __restrict__ qo, u16* __restrict__ ko,
        u16* __restrict__ vo, u16* __restrict__ go){
    __shared__ __align__(16) u16 At[64][264];
    __shared__ __align__(16) u16 Bt[64][264];
    const int cb = blockIdx.x, rb = blockIdx.y;
    const int mat = cb >> 2;
    const float* W = (mat==0)?wq:(mat==1)?wk:(mat==2)?wv:wg;
    const int c0 = (cb&3)*64;
    const int r0 = rb*64;
    const int tid = threadIdx.x;
    const int rr = tid>>5, cc = (tid&31)*8;
    #pragma unroll
    for(int p=0;p<8;p++){
        int r = rr + p*8;
        *(uint4*)&At[r][cc] = *(const uint4*)&x[(size_t)(r0+r)*DM + cc];
    }
    #pragma unroll
    for(int p=0;p<8;p++){
        int r = rr + p*8;
        const float* src = W + (size_t)(c0+r)*DM + cc;
        float4 f0 = *(const float4*)src;
        float4 f1 = *(const float4*)(src+4);
        uint4 o;
        o.x = (unsigned)f2b(f0.x) | ((unsigned)f2b(f0.y)<<16);
        o.y = (unsigned)f2b(f0.z) | ((unsigned)f2b(f0.w)<<16);
        o.z = (unsigned)f2b(f1.x) | ((unsigned)f2b(f1.y)<<16);
        o.w = (unsigned)f2b(f1.z) | ((unsigned)f2b(f1.w)<<16);
        *(uint4*)&Bt[r][cc] = o;
    }
    __syncthreads();
    const int w = tid>>6, lane = tid&63;
    const int l15 = lane&15, lq = lane>>4;
    f32x4 acc[4] = {};
    #pragma unroll
    for(int kk=0; kk<DM; kk+=32){
        bf16x8 a = *(const bf16x8*)&At[w*16 + l15][kk + lq*8];
        #pragma unroll
        for(int nt=0;nt<4;nt++){
            bf16x8 b = *(const bf16x8*)&Bt[nt*16 + l15][kk + lq*8];
            acc[nt] = __builtin_amdgcn_mfma_f32_16x16x32_bf16(a,b,acc[nt],0,0,0);
        }
    }
    const float scaling = 0.17677669529663687f;  // 1/sqrt(32)
    #pragma unroll
    for(int nt=0;nt<4;nt++){
        int c = c0 + nt*16 + l15;
        float bgv = (mat==3) ? bg[c] : 0.f;
        #pragma unroll
        for(int rg=0;rg<4;rg++){
            size_t r = (size_t)(r0 + w*16 + lq*4 + rg);
            float a_ = acc[nt][rg];
            if(mat==0)      qo[r*DM + c] = f2b(a_*scaling);
            else if(mat==1) ko[r*DM + c] = f2b(a_);
            else if(mat==2) vo[r*DM + c] = f2b(a_);
            else            go[r*DM + c] = f2b(1.f/(1.f+__expf(-(a_+bgv))));
        }
    }
}

// ---------------- Kernel 3: column attention + gate ----------------
__global__ __launch_bounds__(256) void k_attn(const u16* __restrict__ q,
        const u16* __restrict__ k, const u16* __restrict__ v,
        const u16* __restrict__ g, u16* __restrict__ ao){
    __shared__ __align__(16) u16 Qs[64][40];
    __shared__ __align__(16) u16 Ks[256][40];
    __shared__ __align__(16) u16 VTs[32][264];
    __shared__ __align__(16) u16 Ps[4][16][264];
    const int qt = blockIdx.x, h = blockIdx.y, l = blockIdx.z;
    const int tid = threadIdx.x;
    const int rr = tid>>3;          // 0..31
    const int cc = (tid&7)*4;       // 0..28 (u16 units)
    const int cbase = h*DH;
    #pragma unroll
    for(int p=0;p<2;p++){
        int i = rr + p*32;
        *(uint2*)&Qs[i][cc] = *(const uint2*)&q[((size_t)(qt*64+i)*L_RES + l)*DM + cbase + cc];
    }
    #pragma unroll
    for(int p=0;p<8;p++){
        int i = rr + p*32;
        *(uint2*)&Ks[i][cc] = *(const uint2*)&k[((size_t)i*L_RES + l)*DM + cbase + cc];
    }
    #pragma unroll
    for(int p=0;p<8;p++){
        int i = rr + p*32;
        ushort4 t = *(const ushort4*)&v[((size_t)i*L_RES + l)*DM + cbase + cc];
        VTs[cc+0][i] = t.x; VTs[cc+1][i] = t.y; VTs[cc+2][i] = t.z; VTs[cc+3][i] = t.w;
    }
    __syncthreads();
    const int w = tid>>6, lane = tid&63;
    const int l15 = lane&15, lq = lane>>4;
    // S = q @ k^T : 16 q-rows per wave x 256 keys
    f32x4 sacc[16];
    {
        bf16x8 aq = *(const bf16x8*)&Qs[w*16 + l15][lq*8];
        #pragma unroll
        for(int t=0;t<16;t++){
            bf16x8 bk = *(const bf16x8*)&Ks[t*16 + l15][lq*8];
            f32x4 z = {};
            sacc[t] = __builtin_amdgcn_mfma_f32_16x16x32_bf16(aq,bk,z,0,0,0);
        }
    }
    // softmax over keys; row = lq*4+rg, cols = t*16 + (lane&15) within 16-lane group
    #pragma unroll
    for(int rg=0;rg<4;rg++){
        float mx = sacc[0][rg];
        #pragma unroll
        for(int t=1;t<16;t++) mx = fmaxf(mx, sacc[t][rg]);
        #pragma unroll
        for(int d=1; d<16; d<<=1) mx = fmaxf(mx, __shfl_xor(mx, d));
        float sum = 0.f;
        #pragma unroll
        for(int t=0;t<16;t++){ float e = __expf(sacc[t][rg]-mx); sacc[t][rg]=e; sum += e; }
        #pragma unroll
        for(int d=1; d<16; d<<=1) sum += __shfl_xor(sum, d);
        float rinv = 1.f/sum;
        #pragma unroll
        for(int t=0;t<16;t++) sacc[t][rg] *= rinv;
    }
    // P -> LDS (layout change for A-fragment)
    #pragma unroll
    for(int t=0;t<16;t++){
        #pragma unroll
        for(int rg=0;rg<4;rg++)
            Ps[w][lq*4+rg][t*16 + l15] = f2b(sacc[t][rg]);
    }
    // out = P @ V  (V transposed in LDS -> contiguous B-fragments)
    f32x4 oacc[2] = {};
    #pragma unroll
    for(int kt=0;kt<8;kt++){
        bf16x8 ap = *(const bf16x8*)&Ps[w][l15][kt*32 + lq*8];
        #pragma unroll
        for(int nt=0;nt<2;nt++){
            bf16x8 bv = *(const bf16x8*)&VTs[nt*16 + l15][kt*32 + lq*8];
            oacc[nt] = __builtin_amdgcn_mfma_f32_16x16x32_bf16(ap,bv,oacc[nt],0,0,0);
        }
    }
    // gate + store
    #pragma unroll
    for(int nt=0;nt<2;nt++){
        int c = cbase + nt*16 + l15;
        #pragma unroll
        for(int rg=0;rg<4;rg++){
            size_t qn = (size_t)(qt*64 + w*16 + lq*4 + rg);
            size_t idx = (qn*L_RES + l)*DM + c;
            ao[idx] = f2b(b2f(g[idx]) * oacc[nt][rg]);
        }
    }
}

// ---------------- Kernel 4: output projection ----------------
__global__ __launch_bounds__(256) void k_out(const u16* __restrict__ a,
        const float* __restrict__ wo, const float* __restrict__ bo,
        float* __restrict__ out){
    __shared__ __align__(16) u16 At[64][264];
    __shared__ __align__(16) u16 Bt[64][264];
    const int cb = blockIdx.x, rb = blockIdx.y;
    const int c0 = cb*64, r0 = rb*64;
    const int tid = threadIdx.x;
    const int rr = tid>>5, cc = (tid&31)*8;
    #pragma unroll
    for(int p=0;p<8;p++){
        int r = rr + p*8;
        *(uint4*)&At[r][cc] = *(const uint4*)&a[(size_t)(r0+r)*DM + cc];
    }
    #pragma unroll
    for(int p=0;p<8;p++){
        int r = rr + p*8;
        const float* src = wo + (size_t)(c0+r)*DM + cc;
        float4 f0 = *(const float4*)src;
        float4 f1 = *(const float4*)(src+4);
        uint4 o;
        o.x = (unsigned)f2b(f0.x) | ((unsigned)f2b(f0.y)<<16);
        o.y = (unsigned)f2b(f0.z) | ((unsigned)f2b(f0.w)<<16);
        o.z = (unsigned)f2b(f1.x) | ((unsigned)f2b(f1.y)<<16);
        o.w = (unsigned)f2b(f1.z) | ((unsigned)f2b(f1.w)<<16);
        *(uint4*)&Bt[r][cc] = o;
    }
    __syncthreads();
    const int w = tid>>6, lane = tid&63;
    const int l15 = lane&15, lq = lane>>4;
    f32x4 acc[4] = {};
    #pragma unroll
    for(int kk=0;kk<DM;kk+=32){
        bf16x8 av = *(const bf16x8*)&At[w*16 + l15][kk + lq*8];
        #pragma unroll
        for(int nt=0;nt<4;nt++){
            bf16x8 b = *(const bf16x8*)&Bt[nt*16 + l15][kk + lq*8];
            acc[nt] = __builtin_amdgcn_mfma_f32_16x16x32_bf16(av,b,acc[nt],0,0,0);
        }
    }
    #pragma unroll
    for(int nt=0;nt<4;nt++){
        int c = c0 + nt*16 + l15;
        float bov = bo[c];
        #pragma unroll
        for(int rg=0;rg<4;rg++){
            size_t r = (size_t)(r0 + w*16 + lq*4 + rg);
            out[r*DM + c] = acc[nt][rg] + bov;
        }
    }
}

extern "C" void kernel_launch(void* const* d_in, const int* in_sizes, int n_in,
                              void* d_out, int out_size, void* d_ws, size_t ws_size,
                              hipStream_t stream){
    const float* msa = (const float*)d_in[0];
    const float* lnw = (const float*)d_in[1];
    const float* lnb = (const float*)d_in[2];
    const float* wq  = (const float*)d_in[3];
    const float* wk  = (const float*)d_in[4];
    const float* wv  = (const float*)d_in[5];
    const float* wg  = (const float*)d_in[6];
    const float* bg  = (const float*)d_in[7];
    const float* wo  = (const float*)d_in[8];
    const float* bo  = (const float*)d_in[9];
    float* out = (float*)d_out;

    const size_t SEG = (size_t)M_ROWS * DM;   // elements per bf16 buffer
    u16 *xs, *qs, *ks, *vs, *gs, *aos;
    if (ws_size >= 6 * SEG * sizeof(u16)) {
        // Fully separate buffers: no d_out aliasing, no buffer reuse.
        xs  = (u16*)d_ws;
        qs  = xs + SEG;
        ks  = qs + SEG;
        vs  = ks + SEG;
        gs  = vs + SEG;
        aos = gs + SEG;
    } else {
        // Compact fallback: k/v staged in d_out (overwritten by k_out),
        // attention output overwrites x.
        xs  = (u16*)d_ws;
        qs  = xs + SEG;
        gs  = qs + SEG;
        ks  = (u16*)d_out;
        vs  = ks + SEG;
        aos = xs;
    }

    k_ln  <<<M_ROWS/4, 256, 0, stream>>>(msa, lnw, lnb, xs);
    k_qkvg<<<dim3(16, M_ROWS/64), 256, 0, stream>>>(xs, wq, wk, wv, wg, bg, qs, ks, vs, gs);
    k_attn<<<dim3(4, NH, L_RES), 256, 0, stream>>>(qs, ks, vs, gs, aos);
    k_out <<<dim3(4, M_ROWS/64), 256, 0, stream>>>(aos, wo, bo, out);
}

// Round 5
// 372.151 us; speedup vs baseline: 1.2781x; 1.2781x over previous
//
#include <hip/hip_runtime.h>

typedef unsigned short u16;
typedef unsigned int u32;
typedef __attribute__((ext_vector_type(8))) short bf16x8;
typedef __attribute__((ext_vector_type(4))) float f32x4;

#define N_SEQ 256
#define L_RES 384
#define DM 256
#define NH 8
#define DH 32
#define M_ROWS (N_SEQ*L_RES)   // 98304

// swizzled fragment layout (both A-side rows and B-side cols):
//   swz(i,k) = ((i>>4)*32 + (k>>3))*128 + (i&15)*8 + (k&7)
// -> a 16-row (or 16-col) x 256-k tile is 4096 contiguous elements, and an
//    MFMA bf16x8 fragment load is 1KB contiguous across the 64 lanes.

__device__ __forceinline__ u16 f2b(float f){
    unsigned u = __builtin_bit_cast(unsigned, f);
    u = u + 0x7fffu + ((u >> 16) & 1u);
    return (u16)(u >> 16);
}
__device__ __forceinline__ float b2f(u16 b){
    unsigned u = ((unsigned)b) << 16;
    return __builtin_bit_cast(float, u);
}
// LDS bank-conflict XOR swizzle for B tiles (u16 units, keeps 16B alignment):
// injects addr bits 6..8 (l15 bit3 + lq) into bank bits 3..5.
__device__ __forceinline__ int swzB(int a){
    return a ^ (((a>>6)&7)<<3);
}

// ---------------- Kernel 0: weights f32 -> bf16 swizzled ----------------
__global__ __launch_bounds__(256) void k_wcvt(const float* __restrict__ wq,
        const float* __restrict__ wk, const float* __restrict__ wv,
        const float* __restrict__ wg, const float* __restrict__ wo,
        u16* __restrict__ wsw){
    const int mat = blockIdx.x >> 6;
    const float* W = (mat==0)?wq:(mat==1)?wk:(mat==2)?wv:(mat==3)?wg:wo;
    const int r = ((blockIdx.x & 63)*256 + threadIdx.x)*4;   // flat elem idx, %4==0
    const int col = r >> 8, k0 = r & 255;
    float4 f = *(const float4*)&W[r];
    ushort4 o;
    o.x = f2b(f.x); o.y = f2b(f.y); o.z = f2b(f.z); o.w = f2b(f.w);
    const int off = ((col>>4)*32 + (k0>>3))*128 + (col&15)*8 + (k0&7);
    *(ushort4*)&wsw[mat*65536 + off] = o;
}

// ---------------- Kernel 1: LayerNorm -> bf16 x (A-swizzled, direct store) ----------------
__global__ __launch_bounds__(256) void k_ln(const float* __restrict__ msa,
        const float* __restrict__ lnw, const float* __restrict__ lnb,
        u16* __restrict__ xo){
    const int tid = threadIdx.x;
    const int r16 = tid >> 4, lane16 = tid & 15;
    const size_t row = (size_t)blockIdx.x*16 + r16;
    const float4* src = (const float4*)(msa + row*DM + lane16*16);
    float4 a[4];
    float s = 0.f, ss = 0.f;
    #pragma unroll
    for(int j=0;j<4;j++){
        a[j] = src[j];
        s  += a[j].x + a[j].y + a[j].z + a[j].w;
        ss += a[j].x*a[j].x + a[j].y*a[j].y + a[j].z*a[j].z + a[j].w*a[j].w;
    }
    #pragma unroll
    for(int m=1;m<16;m<<=1){ s += __shfl_xor(s,m); ss += __shfl_xor(ss,m); }
    const float mu  = s*(1.f/DM);
    const float inv = rsqrtf(ss*(1.f/DM) - mu*mu + 1e-5f);
    const float4* wv4 = (const float4*)(lnw + lane16*16);
    const float4* bv4 = (const float4*)(lnb + lane16*16);
    u32 pk[8];
    #pragma unroll
    for(int j=0;j<4;j++){
        float4 w = wv4[j], b = bv4[j];
        float e0 = (a[j].x-mu)*inv*w.x + b.x;
        float e1 = (a[j].y-mu)*inv*w.y + b.y;
        float e2 = (a[j].z-mu)*inv*w.z + b.z;
        float e3 = (a[j].w-mu)*inv*w.w + b.w;
        pk[j*2]   = (u32)f2b(e0) | ((u32)f2b(e1)<<16);
        pk[j*2+1] = (u32)f2b(e2) | ((u32)f2b(e3)<<16);
    }
    // cols lane16*16+j*4 -> k-blocks lane16*2 (j=0,1) and lane16*2+1 (j=2,3),
    // each block contiguous 8 u16 at row offset r16*8.
    u16* base = xo + (size_t)blockIdx.x*4096 + lane16*256 + r16*8;
    *(uint4*)base       = *(uint4*)&pk[0];
    *(uint4*)(base+128) = *(uint4*)&pk[4];
}

// ---------------- Kernel 2: fused Q/K/V/G projections ----------------
// A (x) swizzled in global -> coalesced fragment loads, no A-LDS.
// B (weights) swizzled in global -> linear 32KB LDS stage, XOR-swizzled banks.
__global__ __launch_bounds__(256) void k_qkvg(const u16* __restrict__ x,
        const u16* __restrict__ wsw, const float* __restrict__ bg,
        u16* __restrict__ qo, u16* __restrict__ ko,
        u16* __restrict__ vo, u16* __restrict__ go){
    __shared__ __align__(16) u16 Bs[16384];          // 32KB, reused as Ot[128][72]
    const int cb = blockIdx.x, by = blockIdx.y;
    const int mat = cb >> 2, c0 = (cb&3)*64;
    const int tid = threadIdx.x;
    const u16* wt = wsw + mat*65536 + (c0>>4)*4096;  // contiguous 16384-elem tile
    #pragma unroll
    for(int i=0;i<8;i++)
        *(uint4*)&Bs[swzB(i*2048 + tid*8)] = *(const uint4*)&wt[i*2048 + tid*8];
    __syncthreads();
    const int w = tid>>6, lane = tid&63, l15 = lane&15, lq = lane>>4;
    f32x4 acc[2][4] = {};
    const u16* xa = x + ((size_t)by*8 + w*2)*4096;   // wave's 32 rows (2 groups)
    #pragma unroll
    for(int kk=0;kk<8;kk++){
        bf16x8 a0 = *(const bf16x8*)&xa[(kk*4+lq)*128 + l15*8];
        bf16x8 a1 = *(const bf16x8*)&xa[4096 + (kk*4+lq)*128 + l15*8];
        #pragma unroll
        for(int nt=0;nt<4;nt++){
            bf16x8 b = *(const bf16x8*)&Bs[swzB(nt*4096 + (kk*4+lq)*128 + l15*8)];
            acc[0][nt] = __builtin_amdgcn_mfma_f32_16x16x32_bf16(a0,b,acc[0][nt],0,0,0);
            acc[1][nt] = __builtin_amdgcn_mfma_f32_16x16x32_bf16(a1,b,acc[1][nt],0,0,0);
        }
    }
    __syncthreads();                                  // Bs now dead -> reuse as Ot
    u16 (*Ot)[72] = (u16(*)[72])Bs;
    const float scaling = 0.17677669529663687f;       // 1/sqrt(32)
    u16* O = (mat==0)?qo:(mat==1)?ko:(mat==2)?vo:go;
    #pragma unroll
    for(int rt=0;rt<2;rt++){
        #pragma unroll
        for(int nt=0;nt<4;nt++){
            const int c = c0 + nt*16 + l15;
            const float bgv = (mat==3) ? bg[c] : 0.f;
            #pragma unroll
            for(int rg=0;rg<4;rg++){
                float t = acc[rt][nt][rg];
                if(mat==0)      t *= scaling;
                else if(mat==3) t = 1.f/(1.f+__expf(-(t+bgv)));
                Ot[w*32 + rt*16 + lq*4 + rg][nt*16 + l15] = f2b(t);
            }
        }
    }
    __syncthreads();
    {
        const int rowl = tid>>1, half = tid&1;
        const uint4* sp = (const uint4*)&Ot[rowl][half*32];
        uint4* dp = (uint4*)&O[((size_t)by*128 + rowl)*DM + c0 + half*32];
        dp[0]=sp[0]; dp[1]=sp[1]; dp[2]=sp[2]; dp[3]=sp[3];
    }
}

// ---------------- Kernel 3: column attention + gate ----------------
__global__ __launch_bounds__(256) void k_attn(const u16* __restrict__ q,
        const u16* __restrict__ k, const u16* __restrict__ v,
        const u16* __restrict__ g, u16* __restrict__ ao){
    __shared__ __align__(16) u16 Qs[64][40];
    __shared__ __align__(16) u16 Ks[256][40];
    __shared__ __align__(16) u16 VTs[32][264];
    __shared__ __align__(16) u16 Ps[4][16][72];
    const int qt = blockIdx.x, h = blockIdx.y, l = blockIdx.z;
    const int tid = threadIdx.x;
    const int rr = tid>>3;          // 0..31
    const int cc = (tid&7)*4;       // 0..28 (u16 units)
    const int cbase = h*DH;
    #pragma unroll
    for(int p=0;p<2;p++){
        int i = rr + p*32;
        *(uint2*)&Qs[i][cc] = *(const uint2*)&q[((size_t)(qt*64+i)*L_RES + l)*DM + cbase + cc];
    }
    #pragma unroll
    for(int p=0;p<8;p++){
        int i = rr + p*32;
        *(uint2*)&Ks[i][cc] = *(const uint2*)&k[((size_t)i*L_RES + l)*DM + cbase + cc];
    }
    #pragma unroll
    for(int p=0;p<8;p++){
        int i = rr + p*32;
        ushort4 t = *(const ushort4*)&v[((size_t)i*L_RES + l)*DM + cbase + cc];
        VTs[cc+0][i] = t.x; VTs[cc+1][i] = t.y; VTs[cc+2][i] = t.z; VTs[cc+3][i] = t.w;
    }
    __syncthreads();
    const int w = tid>>6, lane = tid&63;
    const int l15 = lane&15, lq = lane>>4;
    // S = q @ k^T : 16 q-rows per wave x 256 keys
    f32x4 sacc[16];
    {
        bf16x8 aq = *(const bf16x8*)&Qs[w*16 + l15][lq*8];
        #pragma unroll
        for(int t=0;t<16;t++){
            bf16x8 bk = *(const bf16x8*)&Ks[t*16 + l15][lq*8];
            f32x4 z = {};
            sacc[t] = __builtin_amdgcn_mfma_f32_16x16x32_bf16(aq,bk,z,0,0,0);
        }
    }
    // softmax over keys (row = lq*4+rg, col = t*16 + l15 within 16-lane group)
    #pragma unroll
    for(int rg=0;rg<4;rg++){
        float mx = sacc[0][rg];
        #pragma unroll
        for(int t=1;t<16;t++) mx = fmaxf(mx, sacc[t][rg]);
        #pragma unroll
        for(int d=1; d<16; d<<=1) mx = fmaxf(mx, __shfl_xor(mx, d));
        float sum = 0.f;
        #pragma unroll
        for(int t=0;t<16;t++){ float e = __expf(sacc[t][rg]-mx); sacc[t][rg]=e; sum += e; }
        #pragma unroll
        for(int d=1; d<16; d<<=1) sum += __shfl_xor(sum, d);
        float rinv = 1.f/sum;
        #pragma unroll
        for(int t=0;t<16;t++) sacc[t][rg] *= rinv;
    }
    // out = P @ V, P chunked through small wave-private LDS (64 keys/chunk)
    f32x4 oacc[2] = {};
    #pragma unroll
    for(int ch=0; ch<4; ch++){
        #pragma unroll
        for(int tt=0; tt<4; tt++){
            const int t = ch*4 + tt;
            #pragma unroll
            for(int rg=0;rg<4;rg++)
                Ps[w][lq*4+rg][tt*16 + l15] = f2b(sacc[t][rg]);
        }
        #pragma unroll
        for(int kt=0;kt<2;kt++){
            bf16x8 ap = *(const bf16x8*)&Ps[w][l15][kt*32 + lq*8];
            #pragma unroll
            for(int nt=0;nt<2;nt++){
                bf16x8 bv = *(const bf16x8*)&VTs[nt*16 + l15][ch*64 + kt*32 + lq*8];
                oacc[nt] = __builtin_amdgcn_mfma_f32_16x16x32_bf16(ap,bv,oacc[nt],0,0,0);
            }
        }
    }
    // gate + store (A-swizzled for k_out)
    #pragma unroll
    for(int nt=0;nt<2;nt++){
        const int c = cbase + nt*16 + l15;
        #pragma unroll
        for(int rg=0;rg<4;rg++){
            const size_t qn = (size_t)(qt*64 + w*16 + lq*4 + rg);
            const size_t m  = qn*L_RES + l;
            const float gv = b2f(g[m*DM + c]);
            ao[((m>>4)*32 + (c>>3))*128 + (m&15)*8 + (c&7)] = f2b(gv * oacc[nt][rg]);
        }
    }
}

// ---------------- Kernel 4: output projection (f32 out + bias) ----------------
__global__ __launch_bounds__(256) void k_out(const u16* __restrict__ a,
        const u16* __restrict__ wsw, const float* __restrict__ bo,
        float* __restrict__ out){
    __shared__ __align__(16) u16 Bs[16384];
    const int cb = blockIdx.x, by = blockIdx.y;
    const int c0 = cb*64;
    const int tid = threadIdx.x;
    const u16* wt = wsw + 4*65536 + (c0>>4)*4096;
    #pragma unroll
    for(int i=0;i<8;i++)
        *(uint4*)&Bs[swzB(i*2048 + tid*8)] = *(const uint4*)&wt[i*2048 + tid*8];
    __syncthreads();
    const int w = tid>>6, lane = tid&63, l15 = lane&15, lq = lane>>4;
    f32x4 acc[2][4] = {};
    const u16* aa = a + ((size_t)by*8 + w*2)*4096;
    #pragma unroll
    for(int kk=0;kk<8;kk++){
        bf16x8 a0 = *(const bf16x8*)&aa[(kk*4+lq)*128 + l15*8];
        bf16x8 a1 = *(const bf16x8*)&aa[4096 + (kk*4+lq)*128 + l15*8];
        #pragma unroll
        for(int nt=0;nt<4;nt++){
            bf16x8 b = *(const bf16x8*)&Bs[swzB(nt*4096 + (kk*4+lq)*128 + l15*8)];
            acc[0][nt] = __builtin_amdgcn_mfma_f32_16x16x32_bf16(a0,b,acc[0][nt],0,0,0);
            acc[1][nt] = __builtin_amdgcn_mfma_f32_16x16x32_bf16(a1,b,acc[1][nt],0,0,0);
        }
    }
    #pragma unroll
    for(int rt=0;rt<2;rt++){
        #pragma unroll
        for(int nt=0;nt<4;nt++){
            const int c = c0 + nt*16 + l15;
            const float bov = bo[c];
            #pragma unroll
            for(int rg=0;rg<4;rg++){
                const size_t r = (size_t)by*128 + w*32 + rt*16 + lq*4 + rg;
                out[r*DM + c] = acc[rt][nt][rg] + bov;
            }
        }
    }
}

extern "C" void kernel_launch(void* const* d_in, const int* in_sizes, int n_in,
                              void* d_out, int out_size, void* d_ws, size_t ws_size,
                              hipStream_t stream){
    const float* msa = (const float*)d_in[0];
    const float* lnw = (const float*)d_in[1];
    const float* lnb = (const float*)d_in[2];
    const float* wq  = (const float*)d_in[3];
    const float* wk  = (const float*)d_in[4];
    const float* wv  = (const float*)d_in[5];
    const float* wg  = (const float*)d_in[6];
    const float* bg  = (const float*)d_in[7];
    const float* wo  = (const float*)d_in[8];
    const float* bo  = (const float*)d_in[9];
    float* out = (float*)d_out;

    const size_t SEG = (size_t)M_ROWS * DM;
    u16 *xs, *qs, *ks, *vs, *gs, *aos, *wsw;
    if (ws_size >= (6*SEG + 5*65536) * sizeof(u16)) {
        xs  = (u16*)d_ws;
        qs  = xs + SEG;
        ks  = qs + SEG;
        vs  = ks + SEG;
        gs  = vs + SEG;
        aos = gs + SEG;
        wsw = aos + SEG;
    } else {
        xs  = (u16*)d_ws;
        qs  = xs + SEG;
        gs  = qs + SEG;
        wsw = gs + SEG;
        ks  = (u16*)d_out;
        vs  = ks + SEG;
        aos = xs;                      // x dead after k_qkvg
    }

    k_wcvt<<<320, 256, 0, stream>>>(wq, wk, wv, wg, wo, wsw);
    k_ln  <<<M_ROWS/16, 256, 0, stream>>>(msa, lnw, lnb, xs);
    k_qkvg<<<dim3(16, M_ROWS/128), 256, 0, stream>>>(xs, wsw, bg, qs, ks, vs, gs);
    k_attn<<<dim3(4, NH, L_RES), 256, 0, stream>>>(qs, ks, vs, gs, aos);
    k_out <<<dim3(4, M_ROWS/128), 256, 0, stream>>>(aos, wsw, bo, out);
}